// Round 8
// baseline (3437.602 us; speedup 1.0000x reference)
//
#include <hip/hip_runtime.h>

// Problem dims
constexpr int kB    = 64;
constexpr int kT    = 512;
constexpr int kDin  = 256;
constexpr int kH    = 1024;
constexpr int kH3   = 3072;
constexpr int kDout = 256;
constexpr int kHB   = kB * kH;   // elements per ring slot (128 KB)

typedef float  f32x4  __attribute__((ext_vector_type(4)));
typedef __bf16 bf16x8 __attribute__((ext_vector_type(8)));
typedef unsigned u32x4 __attribute__((ext_vector_type(4)));
typedef unsigned long long u64;

__device__ __forceinline__ float b2f(unsigned short u) {
  union { float f; unsigned u32; } c; c.u32 = ((unsigned)u) << 16; return c.f;
}
__device__ __forceinline__ unsigned short f2b(float f) {
  union { float f; unsigned u32; } c; c.f = f;
  unsigned r = c.u32 + 0x7fffu + ((c.u32 >> 16) & 1u);  // RNE
  return (unsigned short)(r >> 16);
}
__device__ __forceinline__ bf16x8 ld8(const unsigned short* p) {
  return *reinterpret_cast<const bf16x8*>(p);
}
__device__ __forceinline__ u64 ald(const u64* p) {
  return __hip_atomic_load(p, __ATOMIC_RELAXED, __HIP_MEMORY_SCOPE_AGENT);
}
__device__ __forceinline__ unsigned ald32(const unsigned* p) {
  return __hip_atomic_load(p, __ATOMIC_RELAXED, __HIP_MEMORY_SCOPE_AGENT);
}
__device__ __forceinline__ void ast32(unsigned* p, unsigned v) {
  __hip_atomic_store(p, v, __ATOMIC_RELAXED, __HIP_MEMORY_SCOPE_AGENT);
}
__device__ __forceinline__ float sigm_(float x) { return 1.f / (1.f + __expf(-x)); }
__device__ __forceinline__ float tanh_(float x) {
  return 1.f - 2.f / (__expf(2.f * x) + 1.f);
}

#define MFMA16(a, b, c) __builtin_amdgcn_mfma_f32_16x16x32_bf16((a), (b), (c), 0, 0, 0)

// Swizzled column (in shorts) for linear column C + quad*8 (read side).
__device__ __forceinline__ int swzcol(int C, int quad) {
  return (C & ~63) + ((quad ^ (((C >> 3) ^ (C >> 6)) & 7)) << 3);
}

// Ring slot layout (producer-major): slot = [mtile 4][pidx 64][row 16][col 16]
// elements. Each producer's step output is ONE contiguous 512 B block
// (8 cache lines, exclusively owned -> fast drain, no false sharing).
// Consumer staging re-scatters into the SAME swizzled LDS layout as before:
// 16B chunk c (c = global_col/8) stored at slot (c&~7)|((c^(c>>3))&7).
__device__ __forceinline__ void stage_p(unsigned short (*hl)[1032],
                                        const unsigned short* slotm,  // +mtile*16384
                                        int p, int rg, int rmode) {
  const unsigned short* src = slotm + p * 256 + rg * 64;  // 4 rows x 32B
  const int cb = p * 2;
  if (rmode) {
    u32x4 d[8];
#pragma unroll
    for (int i = 0; i < 4; ++i) {
      d[i * 2]     = *(const u32x4*)(src + i * 16);
      d[i * 2 + 1] = *(const u32x4*)(src + i * 16 + 8);
    }
#pragma unroll
    for (int i = 0; i < 4; ++i)
#pragma unroll
      for (int h = 0; h < 2; ++h) {
        const int c  = cb + h;
        const int so = ((c & ~7) | ((c ^ (c >> 3)) & 7)) * 8;
        *(u32x4*)&hl[rg * 4 + i][so] = d[i * 2 + h];
      }
  } else {
    u64 w[16];
#pragma unroll
    for (int i = 0; i < 16; ++i) w[i] = ald((const u64*)src + i);
#pragma unroll
    for (int i = 0; i < 4; ++i)
#pragma unroll
      for (int h = 0; h < 2; ++h) {
        const int c  = cb + h;
        const int so = ((c & ~7) | ((c ^ (c >> 3)) & 7)) * 8;
        *(u64*)&hl[rg * 4 + i][so]     = w[i * 4 + h * 2];
        *(u64*)&hl[rg * 4 + i][so + 4] = w[i * 4 + h * 2 + 1];
      }
  }
}

// sync[]: 8 replicated regions of 512 u32; producers write all 8, consumers
// poll region blockIdx&7 only.
// ---------------------------------------------------------------------------
__global__ void gru_prep(const float* __restrict__ x,
                         const float* __restrict__ Wi0, const float* __restrict__ Wh0,
                         const float* __restrict__ bi0, const float* __restrict__ bh0,
                         const float* __restrict__ Wi1, const float* __restrict__ Wh1,
                         const float* __restrict__ bi1, const float* __restrict__ bh1,
                         unsigned short* __restrict__ xb,
                         unsigned short* __restrict__ wi0b, unsigned short* __restrict__ wh0b,
                         unsigned short* __restrict__ wi1b, unsigned short* __restrict__ wh1b,
                         unsigned short* __restrict__ r0, unsigned short* __restrict__ r1,
                         float* __restrict__ bias, unsigned* __restrict__ sync) {
  const int stride = gridDim.x * blockDim.x;
  const int g = blockIdx.x * blockDim.x + threadIdx.x;
  for (int i = g; i < kH3 * kDin; i += stride) wi0b[i] = f2b(Wi0[i]);
  for (int i = g; i < kH3 * kH; i += stride) {
    wh0b[i] = f2b(Wh0[i]); wi1b[i] = f2b(Wi1[i]); wh1b[i] = f2b(Wh1[i]);
  }
  for (int i = g; i < kB * kT * kDin; i += stride) xb[i] = f2b(x[i]);
  for (int i = g; i < kHB; i += stride) { r0[i] = 0; r1[i] = 0; }  // slot 0 = h[-1]
  for (int i = g; i < kH; i += stride) {
    bias[0 * kH + i] = bi0[0 * kH + i] + bh0[0 * kH + i];
    bias[1 * kH + i] = bi0[1 * kH + i] + bh0[1 * kH + i];
    bias[2 * kH + i] = bi0[2 * kH + i];
    bias[3 * kH + i] = bh0[2 * kH + i];
    bias[4 * kH + i] = bi1[0 * kH + i] + bh1[0 * kH + i];
    bias[5 * kH + i] = bi1[1 * kH + i] + bh1[1 * kH + i];
    bias[6 * kH + i] = bi1[2 * kH + i];
    bias[7 * kH + i] = bh1[2 * kH + i];
  }
  for (int i = g; i < 4096; i += stride) sync[i] = 0;
}

// ---------------------------------------------------------------------------
// Persistent GRU. 256 blocks x 256 thr. Waves 0-1: L0@t (K-split-2),
// waves 2-3: L1@t-1. Tick-indexed ring (rmode1) / parity-2 (rmode0).
//
// THIS REVISION (serial-chain compression on the R4/R7 base):
//  * B0 removed: ALL waves poll independently (monotone latch, same
//    condition). Staging-write WAR vs prev MFMA-reads is covered by B2 of
//    the previous iteration. 3 barriers/step -> 2, no wake cascade.
//  * Producer-major ring layout: each producer's 16x16 h tile is one
//    contiguous 512B block -> drain touches 8 lines (was 16 scattered),
//    no cross-producer false sharing. LDS layout after staging unchanged.
//  * Flag replicas stored by 8 lanes in parallel (was lane0 x8 serial).
// ---------------------------------------------------------------------------
__global__ void __launch_bounds__(256, 1) gru_main(
    const unsigned short* __restrict__ xb,
    const unsigned short* __restrict__ wi0, const unsigned short* __restrict__ wh0,
    const unsigned short* __restrict__ wi1, const unsigned short* __restrict__ wh1,
    const float* __restrict__ bias,
    unsigned short* __restrict__ r0, unsigned short* __restrict__ r1,
    unsigned* __restrict__ sync, const int rmode,
    const float* __restrict__ Wo, const float* __restrict__ bo,
    float* __restrict__ out) {
  __shared__ unsigned short hl0[16][1032];   // h0[t-1] rows of mtile (swizzled)
  __shared__ unsigned short hl1[16][1032];   // h1[t-2] rows of mtile (swizzled)
  __shared__ float red[2][4][64][5];         // [layer][gate][lane][reg(+pad)]
  __shared__ bf16x8 wlds[2][32][64];         // [kh][0..15 Wh1_z | 16..31 Wh1_n][lane]

  const int tid  = threadIdx.x;
  const int lane = tid & 63;
  const int wv   = tid >> 6;        // 0..3
  const int ln15 = lane & 15;
  const int quad = lane >> 4;

  const int xcd   = blockIdx.x & 7;      // L2-locality heuristic only
  const int rest  = blockIdx.x >> 3;
  const int jsub  = rest & 7;
  const int mtile = rest >> 3;           // 0..3
  const int pidx  = xcd * 8 + jsub;      // producer index 0..63

  const int layer = wv >> 1;             // waves 0,1 -> L0; 2,3 -> L1
  const int kh    = wv & 1;              // K-half
  const int jrow  = xcd * 128 + jsub * 16 + ln15;
  const int jcol  = jrow;

  const unsigned short *pw_r, *pw_z, *pw_n, *pv_r, *pv_z, *pv_n;
  if (layer == 0) {
    pw_r = wh0 + (size_t)(0 * kH + jrow) * kH + kh * 512 + quad * 8;
    pw_z = wh0 + (size_t)(1 * kH + jrow) * kH + kh * 512 + quad * 8;
    pw_n = wh0 + (size_t)(2 * kH + jrow) * kH + kh * 512 + quad * 8;
    pv_r = wi0 + (size_t)(0 * kH + jrow) * kDin + kh * 128 + quad * 8;
    pv_z = wi0 + (size_t)(1 * kH + jrow) * kDin + kh * 128 + quad * 8;
    pv_n = wi0 + (size_t)(2 * kH + jrow) * kDin + kh * 128 + quad * 8;
  } else {
    pw_r = wh1 + (size_t)(0 * kH + jrow) * kH + kh * 512 + quad * 8;
    pw_z = wh1 + (size_t)(1 * kH + jrow) * kH + kh * 512 + quad * 8;
    pw_n = wh1 + (size_t)(2 * kH + jrow) * kH + kh * 512 + quad * 8;
    pv_r = wi1 + (size_t)(0 * kH + jrow) * kH + kh * 512 + quad * 8;
    pv_z = wi1 + (size_t)(1 * kH + jrow) * kH + kh * 512 + quad * 8;
    pv_n = wi1 + (size_t)(2 * kH + jrow) * kH + kh * 512 + quad * 8;
  }

  // Bias scalars, loaded ONCE.
  const float* bb = bias + layer * 4 * kH;
  const float b_r = bb[jcol];
  const float b_z = bb[kH + jcol];
  const float b_i = bb[2 * kH + jcol];
  const float b_h = bb[3 * kH + jcol];

  // ---- persistent weight register file (256 VGPR, shared by both layers) --
  bf16x8 W[64];
  if (layer == 0) {
#pragma unroll
    for (int kk = 0; kk < 16; ++kk) {
      W[kk]      = ld8(pw_r + kk * 32);
      W[16 + kk] = ld8(pw_z + kk * 32);
      W[32 + kk] = ld8(pw_n + kk * 32);
    }
#pragma unroll
    for (int kk = 0; kk < 4; ++kk) {
      W[48 + kk] = ld8(pv_r + kk * 32);
      W[52 + kk] = ld8(pv_z + kk * 32);
      W[56 + kk] = ld8(pv_n + kk * 32);
    }
  } else {
#pragma unroll
    for (int kk = 0; kk < 16; ++kk) {
      W[kk]      = ld8(pv_r + kk * 32);
      W[16 + kk] = ld8(pv_z + kk * 32);
      W[32 + kk] = ld8(pv_n + kk * 32);
      W[48 + kk] = ld8(pw_r + kk * 32);
      wlds[kh][kk][lane]      = ld8(pw_z + kk * 32);
      wlds[kh][16 + kk][lane] = ld8(pw_n + kk * 32);
    }
  }

  const f32x4 z4 = {0.f, 0.f, 0.f, 0.f};
  // Region-local poll pointers; producers broadcast to all regions.
  unsigned* fl0 = sync + (size_t)xcd * 512 + mtile * 64;
  unsigned* fl1 = sync + (size_t)xcd * 512 + 256 + mtile * 64;

  float hprev[4] = {0.f, 0.f, 0.f, 0.f};   // this wave's own h tile at t-1

  // staging identity for this thread (producer-major gather)
  const int sp  = tid & 63;   // producer index to stage
  const int srg = tid >> 6;   // row group 0..3 (rows srg*4..+3)

  for (int t = 0; t <= kT; ++t) {
    const bool l0c = (t < kT);
    const bool l1c = (t >= 1);
    // ring slots (rmode=1: tick index; rmode=0: parity)
    const int s0r = rmode ? t : (t & 1);
    const int s0w = rmode ? (t + 1) : ((t + 1) & 1);
    const int s1r = rmode ? (t >= 1 ? t - 1 : 0) : ((t >= 1 ? t - 1 : 0) & 1);
    const int s1w = rmode ? t : (t & 1);

    f32x4 a_r = z4, a_z = z4, a_i = z4, a_h = z4;

    // x fragment loads + x-part MFMAs (independent of h; overlap the poll)
    if (layer == 0 && l0c) {
      const unsigned short* xp = xb + (size_t)(mtile * 16 + ln15) * (kT * kDin) +
                                 t * kDin + kh * 128 + quad * 8;
      bf16x8 xa[4];
#pragma unroll
      for (int i = 0; i < 4; ++i) xa[i] = ld8(xp + i * 32);
#pragma unroll
      for (int kk = 0; kk < 4; ++kk) {
        a_r = MFMA16(xa[kk], W[48 + kk], a_r);
        a_z = MFMA16(xa[kk], W[52 + kk], a_z);
        a_i = MFMA16(xa[kk], W[56 + kk], a_i);
      }
    }

    // ---- ALL waves poll independently (monotone latch; no B0) -------------
    {
      int first = 1;
      for (;;) {
        int a = (int)ald32(fl0 + lane);
        int b = (int)ald32(fl1 + lane);
        if (__all(a >= t && b >= t - 1)) break;
        if (first) { __builtin_amdgcn_s_sleep(8); first = 0; }
        else       { __builtin_amdgcn_s_sleep(2); }
      }
    }
    // WAR note: staging writes below are ordered after last iteration's
    // MFMA reads of hl0/hl1 by B2(t-1); no barrier needed here.

    // ---- stage h rows of mtile into LDS (producer-major gather) -----------
    stage_p(hl0, r0 + (size_t)s0r * kHB + mtile * 16384, sp, srg, rmode);
    stage_p(hl1, r1 + (size_t)s1r * kHB + mtile * 16384, sp, srg, rmode);
    __syncthreads();  // B1: LDS staged

    // ---- MFMA (A from swizzled LDS; weights from registers / wlds) --------
    const bool active = (layer == 0) ? l0c : l1c;
    if (active) {
      const int kb = kh * 512;
      if (layer == 0) {
#pragma unroll
        for (int kk = 0; kk < 16; ++kk) {
          bf16x8 A = *(const bf16x8*)&hl0[ln15][swzcol(kb + kk * 32, quad)];
          a_r = MFMA16(A, W[kk], a_r);
          a_z = MFMA16(A, W[16 + kk], a_z);
          a_h = MFMA16(A, W[32 + kk], a_h);
        }
      } else {
#pragma unroll
        for (int kk = 0; kk < 16; ++kk) {
          bf16x8 A0 = *(const bf16x8*)&hl0[ln15][swzcol(kb + kk * 32, quad)];
          a_r = MFMA16(A0, W[kk], a_r);
          a_z = MFMA16(A0, W[16 + kk], a_z);
          a_i = MFMA16(A0, W[32 + kk], a_i);
          bf16x8 A1 = *(const bf16x8*)&hl1[ln15][swzcol(kb + kk * 32, quad)];
          a_r = MFMA16(A1, W[48 + kk], a_r);
          a_z = MFMA16(A1, wlds[kh][kk][lane], a_z);
          a_h = MFMA16(A1, wlds[kh][16 + kk][lane], a_h);
        }
      }
    }

    // ---- 2-way K-reduce ---------------------------------------------------
    if (((wv == 1) && l0c) || ((wv == 3) && l1c)) {
#pragma unroll
      for (int q = 0; q < 4; ++q) {
        red[layer][0][lane][q] = a_r[q]; red[layer][1][lane][q] = a_z[q];
        red[layer][2][lane][q] = a_i[q]; red[layer][3][lane][q] = a_h[q];
      }
    }
    __syncthreads();  // B2

    // ---- gates + contiguous h store + parallel flag broadcast -------------
    if (((wv == 0) && l0c) || ((wv == 2) && l1c)) {
      float hv4[4];
#pragma unroll
      for (int q = 0; q < 4; ++q) {
        float sr = a_r[q] + red[layer][0][lane][q];
        float sz = a_z[q] + red[layer][1][lane][q];
        float si = a_i[q] + red[layer][2][lane][q];
        float sh = a_h[q] + red[layer][3][lane][q];
        float rg = sigm_(sr + b_r);
        float zg = sigm_(sz + b_z);
        float ng = tanh_(si + b_i + rg * (sh + b_h));
        hv4[q] = (1.f - zg) * ng + zg * hprev[q];
        hprev[q] = hv4[q];
      }
      unsigned short* dst = ((layer == 0) ? r0 + (size_t)s0w * kHB
                                          : r1 + (size_t)s1w * kHB) +
                            mtile * 16384 + pidx * 256;   // producer-major block
#pragma unroll
      for (int q = 0; q < 4; ++q) {
        float pv = __shfl_xor(hv4[q], 1);
        if (!(lane & 1)) {
          unsigned pk = (unsigned)f2b(hv4[q]) | ((unsigned)f2b(pv) << 16);
          unsigned* d = (unsigned*)(dst + (quad * 4 + q) * 16 + (ln15 & ~1));
          ast32(d, pk);
        }
      }
      // Drain this wave's h stores, then broadcast flag (8 lanes parallel).
      asm volatile("s_waitcnt vmcnt(0)" ::: "memory");
      const int base = (layer == 0) ? (mtile * 64 + pidx)
                                    : (256 + mtile * 64 + pidx);
      const unsigned val = (layer == 0) ? (unsigned)(t + 1) : (unsigned)t;
      if (lane < 8) ast32(sync + lane * 512 + base, val);
    }
    // no B3: red[] WAR covered by B1 of next iteration; hl WAR by B2.
  }

  // ---------------- output projection: out = h1[511] @ Wo^T + bo -----------
  {
    int first = 1;
    for (;;) {
      int f = (int)ald32(fl1 + lane);
      if (__all(f >= (int)kT)) break;
      if (first) { __builtin_amdgcn_s_sleep(8); first = 0; }
      else       { __builtin_amdgcn_s_sleep(2); }
    }
  }
  __syncthreads();
  // stage h1[511] rows of this mtile into LDS (UNswizzled; producer-major src)
  {
    const int sfin = rmode ? kT : 0;   // slot holding h1[511]
    const unsigned short* src =
        r1 + (size_t)sfin * kHB + mtile * 16384 + sp * 256 + srg * 64;
    if (rmode) {
      u32x4 d[8];
#pragma unroll
      for (int i = 0; i < 4; ++i) {
        d[i * 2]     = *(const u32x4*)(src + i * 16);
        d[i * 2 + 1] = *(const u32x4*)(src + i * 16 + 8);
      }
#pragma unroll
      for (int i = 0; i < 4; ++i) {
        *(u32x4*)&hl0[srg * 4 + i][sp * 16]     = d[i * 2];
        *(u32x4*)&hl0[srg * 4 + i][sp * 16 + 8] = d[i * 2 + 1];
      }
    } else {
      u64 w[16];
#pragma unroll
      for (int i = 0; i < 16; ++i) w[i] = ald((const u64*)src + i);
#pragma unroll
      for (int i = 0; i < 4; ++i) {
        *(u64*)&hl0[srg * 4 + i][sp * 16]      = w[i * 4];
        *(u64*)&hl0[srg * 4 + i][sp * 16 + 4]  = w[i * 4 + 1];
        *(u64*)&hl0[srg * 4 + i][sp * 16 + 8]  = w[i * 4 + 2];
        *(u64*)&hl0[srg * 4 + i][sp * 16 + 12] = w[i * 4 + 3];
      }
    }
  }
  __syncthreads();
  {
    const int c  = tid & 31;          // 32 out cols per jsub
    const int rr = tid >> 5;          // rows rr and rr+8
    const int col = jsub * 32 + c;
    const float* wr = Wo + (size_t)col * kH;
    float acc0 = bo[col], acc1 = bo[col];
#pragma unroll 8
    for (int k = 0; k < kH; k += 4) {
      float4 w4 = *reinterpret_cast<const float4*>(wr + k);
      acc0 += b2f(hl0[rr][k]) * w4.x + b2f(hl0[rr][k + 1]) * w4.y +
              b2f(hl0[rr][k + 2]) * w4.z + b2f(hl0[rr][k + 3]) * w4.w;
      acc1 += b2f(hl0[rr + 8][k]) * w4.x + b2f(hl0[rr + 8][k + 1]) * w4.y +
              b2f(hl0[rr + 8][k + 2]) * w4.z + b2f(hl0[rr + 8][k + 3]) * w4.w;
    }
    out[(mtile * 16 + rr) * kDout + col] = acc0;
    out[(mtile * 16 + rr + 8) * kDout + col] = acc1;
  }
}

// ---------------------------------------------------------------------------
extern "C" void kernel_launch(void* const* d_in, const int* in_sizes, int n_in,
                              void* d_out, int out_size, void* d_ws, size_t ws_size,
                              hipStream_t stream) {
  const float* x   = (const float*)d_in[0];
  const float* Wi0 = (const float*)d_in[1];
  const float* Wh0 = (const float*)d_in[2];
  const float* bi0 = (const float*)d_in[3];
  const float* bh0 = (const float*)d_in[4];
  const float* Wi1 = (const float*)d_in[5];
  const float* Wh1 = (const float*)d_in[6];
  const float* bi1 = (const float*)d_in[7];
  const float* bh1 = (const float*)d_in[8];
  const float* Wo  = (const float*)d_in[9];
  const float* bo  = (const float*)d_in[10];

  char* ws = (char*)d_ws;
  size_t off = 0;
  auto take = [&](size_t bytes) {
    size_t r = off;
    off += (bytes + 255) & ~(size_t)255;
    return r;
  };
  unsigned short* xb   = (unsigned short*)(ws + take((size_t)kB * kT * kDin * 2));
  unsigned short* wi0b = (unsigned short*)(ws + take((size_t)kH3 * kDin * 2));
  unsigned short* wh0b = (unsigned short*)(ws + take((size_t)kH3 * kH * 2));
  unsigned short* wi1b = (unsigned short*)(ws + take((size_t)kH3 * kH * 2));
  unsigned short* wh1b = (unsigned short*)(ws + take((size_t)kH3 * kH * 2));
  float*          bias = (float*)(ws + take(8 * kH * sizeof(float)));
  unsigned*       sync = (unsigned*)(ws + take(4096 * sizeof(unsigned)));

  // Ring: 513 slots of 128 KB per layer if workspace allows, else parity-2.
  const size_t slot_b = (size_t)kHB * 2;
  int rmode = 1;
  size_t ring_slots = (size_t)kT + 1;
  if (off + 2 * (ring_slots * slot_b) + (1u << 20) > ws_size) {
    rmode = 0;
    ring_slots = 2;
  }
  unsigned short* r0 = (unsigned short*)(ws + take(ring_slots * slot_b));
  unsigned short* r1 = (unsigned short*)(ws + take(ring_slots * slot_b));

  gru_prep<<<2048, 256, 0, stream>>>(x, Wi0, Wh0, bi0, bh0, Wi1, Wh1, bi1, bh1,
                                     xb, wi0b, wh0b, wi1b, wh1b, r0, r1, bias,
                                     sync);
  gru_main<<<256, 256, 0, stream>>>(xb, wi0b, wh0b, wi1b, wh1b, bias, r0, r1,
                                    sync, rmode, Wo, bo, (float*)d_out);
}

// Round 9
// 3288.172 us; speedup vs baseline: 1.0454x; 1.0454x over previous
//
#include <hip/hip_runtime.h>

// Problem dims
constexpr int kB    = 64;
constexpr int kT    = 512;
constexpr int kDin  = 256;
constexpr int kH    = 1024;
constexpr int kH3   = 3072;
constexpr int kDout = 256;
constexpr int kHB   = kB * kH;   // elements per ring slot (128 KB)

typedef float  f32x4  __attribute__((ext_vector_type(4)));
typedef __bf16 bf16x8 __attribute__((ext_vector_type(8)));
typedef unsigned u32x4 __attribute__((ext_vector_type(4)));
typedef unsigned long long u64;

__device__ __forceinline__ float b2f(unsigned short u) {
  union { float f; unsigned u32; } c; c.u32 = ((unsigned)u) << 16; return c.f;
}
__device__ __forceinline__ unsigned short f2b(float f) {
  union { float f; unsigned u32; } c; c.f = f;
  unsigned r = c.u32 + 0x7fffu + ((c.u32 >> 16) & 1u);  // RNE
  return (unsigned short)(r >> 16);
}
__device__ __forceinline__ bf16x8 ld8(const unsigned short* p) {
  return *reinterpret_cast<const bf16x8*>(p);
}
__device__ __forceinline__ u64 ald(const u64* p) {
  return __hip_atomic_load(p, __ATOMIC_RELAXED, __HIP_MEMORY_SCOPE_AGENT);
}
__device__ __forceinline__ unsigned ald32(const unsigned* p) {
  return __hip_atomic_load(p, __ATOMIC_RELAXED, __HIP_MEMORY_SCOPE_AGENT);
}
__device__ __forceinline__ void ast32(unsigned* p, unsigned v) {
  __hip_atomic_store(p, v, __ATOMIC_RELAXED, __HIP_MEMORY_SCOPE_AGENT);
}
__device__ __forceinline__ float sigm_(float x) { return 1.f / (1.f + __expf(-x)); }
__device__ __forceinline__ float tanh_(float x) {
  return 1.f - 2.f / (__expf(2.f * x) + 1.f);
}

#define MFMA16(a, b, c) __builtin_amdgcn_mfma_f32_16x16x32_bf16((a), (b), (c), 0, 0, 0)

// Swizzled column (in shorts) for linear column C + quad*8 (read side).
__device__ __forceinline__ int swzcol(int C, int quad) {
  return (C & ~63) + ((quad ^ (((C >> 3) ^ (C >> 6)) & 7)) << 3);
}

// Stage one 128B segment (absolute seg index s, 0..15) of a ring row into a
// swizzled LDS row. Same layout as R4/R7 (read side unchanged).
__device__ __forceinline__ void stage_seg(unsigned short* ldsrow,
                                          const unsigned short* src, int s,
                                          int rmode) {
  if (rmode) {
    u32x4 d[8];
#pragma unroll
    for (int i = 0; i < 8; ++i) d[i] = *(const u32x4*)(src + i * 8);
#pragma unroll
    for (int i = 0; i < 8; ++i)
      *(u32x4*)&ldsrow[s * 64 + ((i ^ s) & 7) * 8] = d[i];
  } else {
    u64 w[16];
#pragma unroll
    for (int i = 0; i < 16; ++i) w[i] = ald((const u64*)src + i);
#pragma unroll
    for (int i = 0; i < 16; ++i)
      *(u64*)&ldsrow[s * 64 + (((i >> 1) ^ s) & 7) * 8 + (i & 1) * 4] = w[i];
  }
}

// One wave stages one K-half (16 rows x 512 cols = 16 KB), coalesced:
// lane -> row lane>>2, segments kh*8 + (lane&3)*2 + {0,1}.
__device__ __forceinline__ void stage_half(unsigned short (*hl)[1032],
                                           const unsigned short* rbase,
                                           int kh, int lane, int rmode) {
  const int r = lane >> 2;
  const int s = kh * 8 + (lane & 3) * 2;
  const unsigned short* src = rbase + (size_t)r * kH + s * 64;
  stage_seg(hl[r], src, s, rmode);
  stage_seg(hl[r], src + 64, s + 1, rmode);
}

// LDS pair-sync: monotone counters, workgroup-scope release/acquire.
__device__ __forceinline__ void pb_post(unsigned* p, unsigned v, int lane) {
  if (lane == 0)
    __hip_atomic_store(p, v, __ATOMIC_RELEASE, __HIP_MEMORY_SCOPE_WORKGROUP);
}
__device__ __forceinline__ void pb_wait(unsigned* p, unsigned v) {
  while (__hip_atomic_load(p, __ATOMIC_ACQUIRE, __HIP_MEMORY_SCOPE_WORKGROUP) < v)
    __builtin_amdgcn_s_sleep(1);
}

// sync[]: 8 replicated regions of 512 u32; producers write all 8, consumers
// poll region blockIdx&7 only.
// ---------------------------------------------------------------------------
__global__ void gru_prep(const float* __restrict__ x,
                         const float* __restrict__ Wi0, const float* __restrict__ Wh0,
                         const float* __restrict__ bi0, const float* __restrict__ bh0,
                         const float* __restrict__ Wi1, const float* __restrict__ Wh1,
                         const float* __restrict__ bi1, const float* __restrict__ bh1,
                         unsigned short* __restrict__ xb,
                         unsigned short* __restrict__ wi0b, unsigned short* __restrict__ wh0b,
                         unsigned short* __restrict__ wi1b, unsigned short* __restrict__ wh1b,
                         unsigned short* __restrict__ r0, unsigned short* __restrict__ r1,
                         float* __restrict__ bias, unsigned* __restrict__ sync) {
  const int stride = gridDim.x * blockDim.x;
  const int g = blockIdx.x * blockDim.x + threadIdx.x;
  for (int i = g; i < kH3 * kDin; i += stride) wi0b[i] = f2b(Wi0[i]);
  for (int i = g; i < kH3 * kH; i += stride) {
    wh0b[i] = f2b(Wh0[i]); wi1b[i] = f2b(Wi1[i]); wh1b[i] = f2b(Wh1[i]);
  }
  for (int i = g; i < kB * kT * kDin; i += stride) xb[i] = f2b(x[i]);
  for (int i = g; i < kHB; i += stride) { r0[i] = 0; r1[i] = 0; }  // slot 0 = h[-1]
  for (int i = g; i < kH; i += stride) {
    bias[0 * kH + i] = bi0[0 * kH + i] + bh0[0 * kH + i];
    bias[1 * kH + i] = bi0[1 * kH + i] + bh0[1 * kH + i];
    bias[2 * kH + i] = bi0[2 * kH + i];
    bias[3 * kH + i] = bh0[2 * kH + i];
    bias[4 * kH + i] = bi1[0 * kH + i] + bh1[0 * kH + i];
    bias[5 * kH + i] = bi1[1 * kH + i] + bh1[1 * kH + i];
    bias[6 * kH + i] = bi1[2 * kH + i];
    bias[7 * kH + i] = bh1[2 * kH + i];
  }
  for (int i = g; i < 4096; i += stride) sync[i] = 0;
}

// ---------------------------------------------------------------------------
// Persistent GRU. 256 blocks x 256 thr. Waves: 0=(L0,kh0) 1=(L0,kh1)
// 2=(L1,kh0) 3=(L1,kh1). Tick-indexed ring (rmode1) / parity-2 (rmode0).
//
// THIS REVISION (per-half dataflow decoupling on the R7 base):
//  * NO block-wide barrier in the loop. Wave (layer,kh) polls ONLY the 32
//    producers of its K-half (rmode1); L0 waves don't poll fl1 at all.
//    Convoy width per dependency: 64 -> 32.
//  * Each wave stages its own 16 KB half-tile (hl0 half by L0 wave, hl1
//    half by L1 wave), R7-coalesced + same XOR swizzle.
//  * Cross-wave ordering via 8 monotone LDS counters (acq/rel):
//      stg0/stg1: wv0/wv1 staged hl0-half@t   (waited by wv2/wv3)
//      mf2/mf3:   wv2/wv3 done reading hl0-half@t (waited by wv0/wv1 @t+1)
//      red0/red1: wv1/wv3 wrote red@t          (waited by wv0/wv2)
//      gt0/gt1:   wv0/wv2 read red@t           (waited by wv1/wv3 @t+1)
//    All posts unconditional each step (value t+1) -> counters advance even
//    on inactive edge steps; acyclic per step: wv1 -> wv0 -> wv2, wv1 -> wv3.
//  * rmode0 keeps R7's conservative full-width poll (parity WAR).
// ---------------------------------------------------------------------------
__global__ void __launch_bounds__(256, 1) gru_main(
    const unsigned short* __restrict__ xb,
    const unsigned short* __restrict__ wi0, const unsigned short* __restrict__ wh0,
    const unsigned short* __restrict__ wi1, const unsigned short* __restrict__ wh1,
    const float* __restrict__ bias,
    unsigned short* __restrict__ r0, unsigned short* __restrict__ r1,
    unsigned* __restrict__ sync, const int rmode,
    const float* __restrict__ Wo, const float* __restrict__ bo,
    float* __restrict__ out) {
  __shared__ unsigned short hl0[16][1032];   // h0[t-1] rows of mtile (swizzled)
  __shared__ unsigned short hl1[16][1032];   // h1[t-2] rows of mtile (swizzled)
  __shared__ float red[2][4][64][5];         // [layer][gate][lane][reg(+pad)]
  __shared__ bf16x8 wlds[2][32][64];         // [kh][0..15 Wh1_z | 16..31 Wh1_n][lane]
  __shared__ unsigned pb[8];                 // 0:stg0 1:stg1 2:mf2 3:mf3
                                             // 4:red0 5:red1 6:gt0 7:gt1

  const int tid  = threadIdx.x;
  const int lane = tid & 63;
  const int wv   = tid >> 6;        // 0..3
  const int ln15 = lane & 15;
  const int quad = lane >> 4;

  const int xcd   = blockIdx.x & 7;      // L2-locality heuristic only
  const int rest  = blockIdx.x >> 3;
  const int jsub  = rest & 7;
  const int mtile = rest >> 3;           // 0..3
  const int pidx  = xcd * 8 + jsub;      // producer index 0..63

  const int layer = wv >> 1;             // waves 0,1 -> L0; 2,3 -> L1
  const int kh    = wv & 1;              // K-half
  const int jrow  = xcd * 128 + jsub * 16 + ln15;
  const int jcol  = jrow;

  const unsigned short *pw_r, *pw_z, *pw_n, *pv_r, *pv_z, *pv_n;
  if (layer == 0) {
    pw_r = wh0 + (size_t)(0 * kH + jrow) * kH + kh * 512 + quad * 8;
    pw_z = wh0 + (size_t)(1 * kH + jrow) * kH + kh * 512 + quad * 8;
    pw_n = wh0 + (size_t)(2 * kH + jrow) * kH + kh * 512 + quad * 8;
    pv_r = wi0 + (size_t)(0 * kH + jrow) * kDin + kh * 128 + quad * 8;
    pv_z = wi0 + (size_t)(1 * kH + jrow) * kDin + kh * 128 + quad * 8;
    pv_n = wi0 + (size_t)(2 * kH + jrow) * kDin + kh * 128 + quad * 8;
  } else {
    pw_r = wh1 + (size_t)(0 * kH + jrow) * kH + kh * 512 + quad * 8;
    pw_z = wh1 + (size_t)(1 * kH + jrow) * kH + kh * 512 + quad * 8;
    pw_n = wh1 + (size_t)(2 * kH + jrow) * kH + kh * 512 + quad * 8;
    pv_r = wi1 + (size_t)(0 * kH + jrow) * kH + kh * 512 + quad * 8;
    pv_z = wi1 + (size_t)(1 * kH + jrow) * kH + kh * 512 + quad * 8;
    pv_n = wi1 + (size_t)(2 * kH + jrow) * kH + kh * 512 + quad * 8;
  }

  // Bias scalars, loaded ONCE.
  const float* bb = bias + layer * 4 * kH;
  const float b_r = bb[jcol];
  const float b_z = bb[kH + jcol];
  const float b_i = bb[2 * kH + jcol];
  const float b_h = bb[3 * kH + jcol];

  // ---- persistent weight register file (256 VGPR, shared by both layers) --
  bf16x8 W[64];
  if (layer == 0) {
#pragma unroll
    for (int kk = 0; kk < 16; ++kk) {
      W[kk]      = ld8(pw_r + kk * 32);
      W[16 + kk] = ld8(pw_z + kk * 32);
      W[32 + kk] = ld8(pw_n + kk * 32);
    }
#pragma unroll
    for (int kk = 0; kk < 4; ++kk) {
      W[48 + kk] = ld8(pv_r + kk * 32);
      W[52 + kk] = ld8(pv_z + kk * 32);
      W[56 + kk] = ld8(pv_n + kk * 32);
    }
  } else {
#pragma unroll
    for (int kk = 0; kk < 16; ++kk) {
      W[kk]      = ld8(pv_r + kk * 32);
      W[16 + kk] = ld8(pv_z + kk * 32);
      W[32 + kk] = ld8(pv_n + kk * 32);
      W[48 + kk] = ld8(pw_r + kk * 32);
      wlds[kh][kk][lane]      = ld8(pw_z + kk * 32);
      wlds[kh][16 + kk][lane] = ld8(pw_n + kk * 32);
    }
  }

  if (tid < 8) pb[tid] = 0;
  __syncthreads();   // pb zero + wlds visible (one-time, outside loop)

  const f32x4 z4 = {0.f, 0.f, 0.f, 0.f};
  unsigned* fl0 = sync + (size_t)xcd * 512 + mtile * 64;
  unsigned* fl1 = sync + (size_t)xcd * 512 + 256 + mtile * 64;

  float hprev[4] = {0.f, 0.f, 0.f, 0.f};

  for (int t = 0; t <= kT; ++t) {
    const bool l0c = (t < kT);
    const bool l1c = (t >= 1);
    const int s0r = rmode ? t : (t & 1);
    const int s0w = rmode ? (t + 1) : ((t + 1) & 1);
    const int s1r = rmode ? (t >= 1 ? t - 1 : 0) : ((t >= 1 ? t - 1 : 0) & 1);
    const int s1w = rmode ? t : (t & 1);

    const unsigned short* r0base = r0 + (size_t)s0r * kHB + (size_t)(mtile * 16) * kH;
    const unsigned short* r1base = r1 + (size_t)s1r * kHB + (size_t)(mtile * 16) * kH;
    const int kb = kh * 512;

    if (layer == 0) {
      // =========== L0 wave (kh half) ===========
      f32x4 a_r = z4, a_z = z4, a_i = z4, a_h = z4;
      if (l0c) {   // x part overlaps the poll
        const unsigned short* xp = xb + (size_t)(mtile * 16 + ln15) * (kT * kDin) +
                                   t * kDin + kh * 128 + quad * 8;
        bf16x8 xa[4];
#pragma unroll
        for (int i = 0; i < 4; ++i) xa[i] = ld8(xp + i * 32);
#pragma unroll
        for (int kk = 0; kk < 4; ++kk) {
          a_r = MFMA16(xa[kk], W[48 + kk], a_r);
          a_z = MFMA16(xa[kk], W[52 + kk], a_z);
          a_i = MFMA16(xa[kk], W[56 + kk], a_i);
        }
      }
      {  // poll: rmode1 -> own half of fl0 only; rmode0 -> full (parity WAR)
        int first = 1;
        for (;;) {
          bool ok;
          if (rmode) {
            int a = (int)ald32(fl0 + kh * 32 + (lane & 31));
            ok = __all(a >= t);
          } else {
            int a = (int)ald32(fl0 + lane);
            int b = (int)ald32(fl1 + lane);
            ok = __all(a >= t && b >= t - 1);
          }
          if (ok) break;
          if (first) { __builtin_amdgcn_s_sleep(8); first = 0; }
          else       { __builtin_amdgcn_s_sleep(2); }
        }
      }
      pb_wait(&pb[2 + kh], t);           // L1 partner done reading hl0-half@t-1
      stage_half(hl0, r0base, kh, lane, rmode);
      pb_post(&pb[0 + kh], t + 1, lane); // hl0-half@t staged
      if (l0c) {
#pragma unroll
        for (int kk = 0; kk < 16; ++kk) {
          bf16x8 A = *(const bf16x8*)&hl0[ln15][swzcol(kb + kk * 32, quad)];
          a_r = MFMA16(A, W[kk], a_r);
          a_z = MFMA16(A, W[16 + kk], a_z);
          a_h = MFMA16(A, W[32 + kk], a_h);
        }
      }
      if (kh == 0) {
        // wv0: consumer of red[0], producer of h0
        pb_wait(&pb[4], t + 1);          // wv1 wrote red[0]@t
        if (l0c) {
          float hv4[4];
#pragma unroll
          for (int q = 0; q < 4; ++q) {
            float sr = a_r[q] + red[0][0][lane][q];
            float sz = a_z[q] + red[0][1][lane][q];
            float si = a_i[q] + red[0][2][lane][q];
            float sh = a_h[q] + red[0][3][lane][q];
            float rg = sigm_(sr + b_r);
            float zg = sigm_(sz + b_z);
            float ng = tanh_(si + b_i + rg * (sh + b_h));
            hv4[q] = (1.f - zg) * ng + zg * hprev[q];
            hprev[q] = hv4[q];
          }
          unsigned short* dst = r0 + (size_t)s0w * kHB;
#pragma unroll
          for (int q = 0; q < 4; ++q) {
            float pv = __shfl_xor(hv4[q], 1);
            if (!(lane & 1)) {
              unsigned pk = (unsigned)f2b(hv4[q]) | ((unsigned)f2b(pv) << 16);
              ast32((unsigned*)(dst + (size_t)(mtile * 16 + quad * 4 + q) * kH +
                                (jcol & ~1)),
                    pk);
            }
          }
          asm volatile("s_waitcnt vmcnt(0)" ::: "memory");
          if (lane < 8) ast32(sync + lane * 512 + mtile * 64 + pidx, (unsigned)(t + 1));
        }
        pb_post(&pb[6], t + 1, lane);    // red[0]@t consumed
      } else {
        // wv1: producer of red[0]
        pb_wait(&pb[6], t);              // wv0 read red[0]@t-1
        if (l0c) {
#pragma unroll
          for (int q = 0; q < 4; ++q) {
            red[0][0][lane][q] = a_r[q]; red[0][1][lane][q] = a_z[q];
            red[0][2][lane][q] = a_i[q]; red[0][3][lane][q] = a_h[q];
          }
        }
        pb_post(&pb[4], t + 1, lane);    // red[0]@t written
      }
    } else {
      // =========== L1 wave (kh half) ===========
      {  // poll: data deps for this half (rmode0: full-width parity WAR)
        int first = 1;
        for (;;) {
          bool ok;
          if (rmode) {
            int a = (int)ald32(fl0 + kh * 32 + (lane & 31));
            int b = (int)ald32(fl1 + kh * 32 + (lane & 31));
            ok = __all(a >= t && b >= t - 1);
          } else {
            int a = (int)ald32(fl0 + lane);
            int b = (int)ald32(fl1 + lane);
            ok = __all(a >= t && b >= t - 1);
          }
          if (ok) break;
          if (first) { __builtin_amdgcn_s_sleep(8); first = 0; }
          else       { __builtin_amdgcn_s_sleep(2); }
        }
      }
      stage_half(hl1, r1base, kh, lane, rmode);  // own-half h1[t-2]
      pb_wait(&pb[0 + kh], t + 1);       // L0 partner staged hl0-half@t
      f32x4 a_r = z4, a_z = z4, a_i = z4, a_h = z4;
      if (l1c) {
#pragma unroll
        for (int kk = 0; kk < 16; ++kk) {
          bf16x8 A0 = *(const bf16x8*)&hl0[ln15][swzcol(kb + kk * 32, quad)];
          a_r = MFMA16(A0, W[kk], a_r);
          a_z = MFMA16(A0, W[16 + kk], a_z);
          a_i = MFMA16(A0, W[32 + kk], a_i);
          bf16x8 A1 = *(const bf16x8*)&hl1[ln15][swzcol(kb + kk * 32, quad)];
          a_r = MFMA16(A1, W[48 + kk], a_r);
          a_z = MFMA16(A1, wlds[kh][kk][lane], a_z);
          a_h = MFMA16(A1, wlds[kh][16 + kk][lane], a_h);
        }
      }
      pb_post(&pb[2 + kh], t + 1, lane); // done reading hl0-half@t
      if (kh == 0) {
        // wv2: consumer of red[1], producer of h1
        pb_wait(&pb[5], t + 1);          // wv3 wrote red[1]@t
        if (l1c) {
          float hv4[4];
#pragma unroll
          for (int q = 0; q < 4; ++q) {
            float sr = a_r[q] + red[1][0][lane][q];
            float sz = a_z[q] + red[1][1][lane][q];
            float si = a_i[q] + red[1][2][lane][q];
            float sh = a_h[q] + red[1][3][lane][q];
            float rg = sigm_(sr + b_r);
            float zg = sigm_(sz + b_z);
            float ng = tanh_(si + b_i + rg * (sh + b_h));
            hv4[q] = (1.f - zg) * ng + zg * hprev[q];
            hprev[q] = hv4[q];
          }
          unsigned short* dst = r1 + (size_t)s1w * kHB;
#pragma unroll
          for (int q = 0; q < 4; ++q) {
            float pv = __shfl_xor(hv4[q], 1);
            if (!(lane & 1)) {
              unsigned pk = (unsigned)f2b(hv4[q]) | ((unsigned)f2b(pv) << 16);
              ast32((unsigned*)(dst + (size_t)(mtile * 16 + quad * 4 + q) * kH +
                                (jcol & ~1)),
                    pk);
            }
          }
          asm volatile("s_waitcnt vmcnt(0)" ::: "memory");
          if (lane < 8)
            ast32(sync + lane * 512 + 256 + mtile * 64 + pidx, (unsigned)t);
        }
        pb_post(&pb[7], t + 1, lane);    // red[1]@t consumed
      } else {
        // wv3: producer of red[1]
        pb_wait(&pb[7], t);              // wv2 read red[1]@t-1
        if (l1c) {
#pragma unroll
          for (int q = 0; q < 4; ++q) {
            red[1][0][lane][q] = a_r[q]; red[1][1][lane][q] = a_z[q];
            red[1][2][lane][q] = a_i[q]; red[1][3][lane][q] = a_h[q];
          }
        }
        pb_post(&pb[5], t + 1, lane);    // red[1]@t written
      }
    }
  }

  // ---------------- output projection: out = h1[511] @ Wo^T + bo -----------
  if (wv == 0) {
    int first = 1;
    for (;;) {
      int f = (int)ald32(fl1 + lane);
      if (__all(f >= (int)kT)) break;
      if (first) { __builtin_amdgcn_s_sleep(8); first = 0; }
      else       { __builtin_amdgcn_s_sleep(2); }
    }
  }
  __syncthreads();
  // stage h1[511] rows of this mtile into LDS (UNswizzled; one-time)
  {
    const int sfin = rmode ? kT : 0;   // slot holding h1[511]
    const int r = tid >> 4, s = tid & 15;
    const unsigned short* b1 =
        r1 + (size_t)sfin * kHB + (size_t)(mtile * 16 + r) * kH + s * 64;
    if (rmode) {
      u32x4 d[8];
#pragma unroll
      for (int i = 0; i < 8; ++i) d[i] = *(const u32x4*)(b1 + i * 8);
#pragma unroll
      for (int i = 0; i < 8; ++i) *(u32x4*)&hl0[r][s * 64 + i * 8] = d[i];
    } else {
      u64 w[16];
#pragma unroll
      for (int i = 0; i < 16; ++i) w[i] = ald((const u64*)b1 + i);
#pragma unroll
      for (int i = 0; i < 16; ++i) *(u64*)&hl0[r][s * 64 + i * 4] = w[i];
    }
  }
  __syncthreads();
  {
    const int c  = tid & 31;          // 32 out cols per jsub
    const int rr = tid >> 5;          // rows rr and rr+8
    const int col = jsub * 32 + c;
    const float* wr = Wo + (size_t)col * kH;
    float acc0 = bo[col], acc1 = bo[col];
#pragma unroll 8
    for (int k = 0; k < kH; k += 4) {
      float4 w4 = *reinterpret_cast<const float4*>(wr + k);
      acc0 += b2f(hl0[rr][k]) * w4.x + b2f(hl0[rr][k + 1]) * w4.y +
              b2f(hl0[rr][k + 2]) * w4.z + b2f(hl0[rr][k + 3]) * w4.w;
      acc1 += b2f(hl0[rr + 8][k]) * w4.x + b2f(hl0[rr + 8][k + 1]) * w4.y +
              b2f(hl0[rr + 8][k + 2]) * w4.z + b2f(hl0[rr + 8][k + 3]) * w4.w;
    }
    out[(mtile * 16 + rr) * kDout + col] = acc0;
    out[(mtile * 16 + rr + 8) * kDout + col] = acc1;
  }
}

// ---------------------------------------------------------------------------
extern "C" void kernel_launch(void* const* d_in, const int* in_sizes, int n_in,
                              void* d_out, int out_size, void* d_ws, size_t ws_size,
                              hipStream_t stream) {
  const float* x   = (const float*)d_in[0];
  const float* Wi0 = (const float*)d_in[1];
  const float* Wh0 = (const float*)d_in[2];
  const float* bi0 = (const float*)d_in[3];
  const float* bh0 = (const float*)d_in[4];
  const float* Wi1 = (const float*)d_in[5];
  const float* Wh1 = (const float*)d_in[6];
  const float* bi1 = (const float*)d_in[7];
  const float* bh1 = (const float*)d_in[8];
  const float* Wo  = (const float*)d_in[9];
  const float* bo  = (const float*)d_in[10];

  char* ws = (char*)d_ws;
  size_t off = 0;
  auto take = [&](size_t bytes) {
    size_t r = off;
    off += (bytes + 255) & ~(size_t)255;
    return r;
  };
  unsigned short* xb   = (unsigned short*)(ws + take((size_t)kB * kT * kDin * 2));
  unsigned short* wi0b = (unsigned short*)(ws + take((size_t)kH3 * kDin * 2));
  unsigned short* wh0b = (unsigned short*)(ws + take((size_t)kH3 * kH * 2));
  unsigned short* wi1b = (unsigned short*)(ws + take((size_t)kH3 * kH * 2));
  unsigned short* wh1b = (unsigned short*)(ws + take((size_t)kH3 * kH * 2));
  float*          bias = (float*)(ws + take(8 * kH * sizeof(float)));
  unsigned*       sync = (unsigned*)(ws + take(4096 * sizeof(unsigned)));

  // Ring: 513 slots of 128 KB per layer if workspace allows, else parity-2.
  const size_t slot_b = (size_t)kHB * 2;
  int rmode = 1;
  size_t ring_slots = (size_t)kT + 1;
  if (off + 2 * (ring_slots * slot_b) + (1u << 20) > ws_size) {
    rmode = 0;
    ring_slots = 2;
  }
  unsigned short* r0 = (unsigned short*)(ws + take(ring_slots * slot_b));
  unsigned short* r1 = (unsigned short*)(ws + take(ring_slots * slot_b));

  gru_prep<<<2048, 256, 0, stream>>>(x, Wi0, Wh0, bi0, bh0, Wi1, Wh1, bi1, bh1,
                                     xb, wi0b, wh0b, wi1b, wh1b, r0, r1, bias,
                                     sync);
  gru_main<<<256, 256, 0, stream>>>(xb, wi0b, wh0b, wi1b, wh1b, bias, r0, r1,
                                    sync, rmode, Wo, bo, (float*)d_out);
}